// Round 1
// baseline (210.350 us; speedup 1.0000x reference)
//
#include <hip/hip_runtime.h>

// B=2, S=2048, E=1024, H=16, D=64; rows = B*S = 4096; 3E = 3072.

typedef __attribute__((ext_vector_type(8))) short short8;     // 8 bf16 (A/B frag, x32)
typedef __attribute__((ext_vector_type(4))) short short4b;    // 4 bf16 (A/B frag, x16)
typedef __attribute__((ext_vector_type(4))) float floatx4;    // C/D frag
typedef unsigned short ushort_t;

static __device__ __forceinline__ ushort_t f2bf(float f) {
    unsigned u = __float_as_uint(f);
    u += 0x7fffu + ((u >> 16) & 1u);      // round-to-nearest-even
    return (ushort_t)(u >> 16);
}
static __device__ __forceinline__ float bf2f(ushort_t h) {
    return __uint_as_float(((unsigned)h) << 16);
}
#if __has_builtin(__builtin_amdgcn_cvt_pk_bf16_f32)
typedef __attribute__((ext_vector_type(2))) __bf16 bf16x2_t;
static __device__ __forceinline__ unsigned pack2bf(float a, float b) {
    bf16x2_t r = __builtin_amdgcn_cvt_pk_bf16_f32(a, b);
    return __builtin_bit_cast(unsigned, r);
}
#else
static __device__ __forceinline__ unsigned pack2bf(float a, float b) {
    return (unsigned)f2bf(a) | ((unsigned)f2bf(b) << 16);
}
#endif
static __device__ __forceinline__ float hexp2(float x) {
    return __builtin_amdgcn_exp2f(x);
}
// async global->LDS, 16B per lane; LDS dest = wave-uniform base + lane*16
static __device__ __forceinline__ void gload16(const void* g, void* l) {
    __builtin_amdgcn_global_load_lds(
        (const __attribute__((address_space(1))) unsigned int*)g,
        (__attribute__((address_space(3))) unsigned int*)l, 16, 0, 0);
}

// 16x16x16 bf16 MFMA: A/B = 4 bf16 (2 VGPRs). Builtin name varies by ROCm;
// hedge with the gfx90a-era name and an asm fallback (ISA: v_mfma_f32_16x16x16_bf16).
static __device__ __forceinline__ floatx4 mfma16(short4b a, short4b b, floatx4 c) {
#if __has_builtin(__builtin_amdgcn_mfma_f32_16x16x16_bf16)
    return __builtin_amdgcn_mfma_f32_16x16x16_bf16(a, b, c, 0, 0, 0);
#elif __has_builtin(__builtin_amdgcn_mfma_f32_16x16x16bf16_1k)
    return __builtin_amdgcn_mfma_f32_16x16x16bf16_1k(a, b, c, 0, 0, 0);
#else
    asm("v_mfma_f32_16x16x16_bf16 %0, %1, %2, %0" : "+v"(c) : "v"(a), "v"(b));
    return c;
#endif
}

// ---------------- fused prep kernel ----------------
// [0,4096):       x fp32 -> xb bf16
// [4096,7168):    Wqkv[K,N] -> wqT[N,K] bf16 (32x32 tiles; id%96 = nb, id/96 = kb)
// [7168,8192):    Wout -> woT
// [8192,8208):    mask -> maddg
__global__ __launch_bounds__(256) void prep(
    const float* __restrict__ x, ushort_t* __restrict__ xb,
    const float* __restrict__ Wqkv, ushort_t* __restrict__ wqT,
    const float* __restrict__ Wout, ushort_t* __restrict__ woT,
    const int* __restrict__ mask, float* __restrict__ maddg)
{
    __shared__ float tile[32][33];
    const int bk = blockIdx.x;
    const int t = threadIdx.x;
    if (bk < 4096) {
        int i = bk * 256 + t;
        float4 v = ((const float4*)x)[i];
        uint2 o;
        o.x = pack2bf(v.x, v.y);
        o.y = pack2bf(v.z, v.w);
        ((uint2*)xb)[i] = o;
        return;
    }
    if (bk < 8192) {
        const float* W; ushort_t* WT; int K, N, id;
        if (bk < 7168) { W = Wqkv; WT = wqT; K = 1024; N = 3072; id = bk - 4096;
                         int nb = (id % 96) * 32, kb = (id / 96) * 32;
                         const int r = t >> 3, c4 = (t & 7) * 4;
                         float4 v = *(const float4*)&W[(size_t)(kb + r) * N + nb + c4];
                         tile[r][c4+0]=v.x; tile[r][c4+1]=v.y; tile[r][c4+2]=v.z; tile[r][c4+3]=v.w;
                         __syncthreads();
                         uint2 o;
                         o.x = pack2bf(tile[c4+0][r], tile[c4+1][r]);
                         o.y = pack2bf(tile[c4+2][r], tile[c4+3][r]);
                         ((uint2*)WT)[((size_t)(nb + r) * K + kb + c4) >> 2] = o;
        } else {         W = Wout; WT = woT; K = 1024; N = 1024; id = bk - 7168;
                         int nb = (id % 32) * 32, kb = (id / 32) * 32;
                         const int r = t >> 3, c4 = (t & 7) * 4;
                         float4 v = *(const float4*)&W[(size_t)(kb + r) * N + nb + c4];
                         tile[r][c4+0]=v.x; tile[r][c4+1]=v.y; tile[r][c4+2]=v.z; tile[r][c4+3]=v.w;
                         __syncthreads();
                         uint2 o;
                         o.x = pack2bf(tile[c4+0][r], tile[c4+1][r]);
                         o.y = pack2bf(tile[c4+2][r], tile[c4+3][r]);
                         ((uint2*)WT)[((size_t)(nb + r) * K + kb + c4) >> 2] = o;
        }
        return;
    }
    {
        int i = (bk - 8192) * 256 + t;      // 4096 total
        maddg[i] = (mask[i] ? 0.f : -1e30f) - 24.0f;
    }
}

// ---------------- GEMM1: qkv projection ----------------
// A=xb[4096,1024], B=wqT[3072,1024]; n<2048 -> qkvb[row][n] (stride 2048);
// n>=2048 (V) -> vtg[b][h][d][s] via LDS bounce (coalesced b128 stores).
__global__ __launch_bounds__(256, 3) void gemm_qkv(
    const ushort_t* __restrict__ A, const ushort_t* __restrict__ B,
    const float* __restrict__ bias, ushort_t* __restrict__ qkvb,
    ushort_t* __restrict__ vtg)
{
    const int K = 1024;
    __shared__ ushort_t Ah[128][32], Bh[128][32];
    __shared__ ushort_t Tb[64][136];         // V-transpose bounce, 16B-aligned rows
    const int bn = blockIdx.x * 128, bm = blockIdx.y * 128;
    const int t = threadIdx.x, w = t >> 6, lane = t & 63;
    const int l15 = lane & 15, quad = lane >> 4;
    const int wm = w >> 1, wn = w & 1;

    const int srow = w * 32 + (lane >> 2);
    const int skp  = (lane & 3) ^ ((lane >> 2) & 3);     // swizzled global k-part
    const int scol = skp * 8;
    const ushort_t* ga = A + (size_t)(bm + srow) * K + scol;
    const ushort_t* gb = B + (size_t)(bn + srow) * K + scol;
    const size_t rstep = (size_t)16 * K;
    const int fcol = ((quad ^ (l15 & 3)) * 8);           // frag read col (deswizzle)

    floatx4 acc[4][4];
    #pragma unroll
    for (int mt = 0; mt < 4; ++mt)
        #pragma unroll
        for (int nt = 0; nt < 4; ++nt) acc[mt][nt] = (floatx4){0.f, 0.f, 0.f, 0.f};

    for (int k0 = 0; k0 < K; k0 += 32) {
        #pragma unroll
        for (int i = 0; i < 2; ++i) {
            gload16(ga + i * rstep + k0, &Ah[w * 32 + i * 16][0]);
            gload16(gb + i * rstep + k0, &Bh[w * 32 + i * 16][0]);
        }
        __syncthreads();
        short8 ah[4], bh[4];
        #pragma unroll
        for (int x = 0; x < 4; ++x) {
            ah[x] = *(const short8*)&Ah[wm * 64 + x * 16 + l15][fcol];
            bh[x] = *(const short8*)&Bh[wn * 64 + x * 16 + l15][fcol];
        }
        #pragma unroll
        for (int mt = 0; mt < 4; ++mt)
            #pragma unroll
            for (int nt = 0; nt < 4; ++nt)
                acc[mt][nt] = __builtin_amdgcn_mfma_f32_16x16x32_bf16(ah[mt], bh[nt], acc[mt][nt], 0, 0, 0);
        __syncthreads();
    }

    if (bn < 2048) {
        // Q,K block: row-major store into qkvb (stride 2048)
        #pragma unroll
        for (int mt = 0; mt < 4; ++mt)
            #pragma unroll
            for (int r = 0; r < 4; ++r) {
                size_t row = (size_t)(bm + wm * 64 + mt * 16 + quad * 4 + r) * 2048;
                #pragma unroll
                for (int nt = 0; nt < 4; ++nt) {
                    int col = bn + wn * 64 + nt * 16 + l15;
                    qkvb[row + col] = f2bf(acc[mt][nt][r] + bias[col]);
                }
            }
    } else {
        // V block: LDS bounce -> vtg[b][h][d][s], one head (64 d) per pass
        const int h0 = (bn - 2048) >> 6;
        const int b  = bm >> 11, s0 = bm & 2047;
        #pragma unroll
        for (int hh = 0; hh < 2; ++hh) {
            if (wn == hh) {
                #pragma unroll
                for (int mt = 0; mt < 4; ++mt)
                    #pragma unroll
                    for (int nt = 0; nt < 4; ++nt) {
                        int d = nt * 16 + l15;
                        int sb = wm * 64 + mt * 16 + quad * 4;
                        float bv = bias[bn + hh * 64 + nt * 16 + l15];
                        uint2 pk;
                        pk.x = pack2bf(acc[mt][nt][0] + bv, acc[mt][nt][1] + bv);
                        pk.y = pack2bf(acc[mt][nt][2] + bv, acc[mt][nt][3] + bv);
                        *(uint2*)&Tb[d][sb] = pk;
                    }
            }
            __syncthreads();
            ushort_t* vbase = vtg + ((size_t)((b * 16 + h0 + hh) * 64)) * 2048 + s0;
            #pragma unroll
            for (int it = 0; it < 4; ++it) {
                int idx = t + it * 256;          // 0..1023
                int d = idx >> 4, ch = idx & 15;
                uint4 v = *(const uint4*)&Tb[d][ch * 8];
                *(uint4*)&vbase[(size_t)d * 2048 + ch * 8] = v;
            }
            __syncthreads();
        }
    }
}

// ---------------- GEMM3: 64x128 tile, fp32 output ----------------
__global__ __launch_bounds__(256, 3) void gemm_bf16_f32_64(
    const ushort_t* __restrict__ A, const ushort_t* __restrict__ B,
    const float* __restrict__ bias, float* __restrict__ C,
    int M, int N, int K)
{
    __shared__ ushort_t Ah[64][32], Bh[128][32];
    const int bn = blockIdx.x * 128, bm = blockIdx.y * 64;
    const int t = threadIdx.x, w = t >> 6, lane = t & 63;
    const int l15 = lane & 15, quad = lane >> 4;
    const int wm = w >> 1, wn = w & 1;          // wave-tile 32x64

    const int srow = w * 16 + (lane >> 2);
    const int skp  = (lane & 3) ^ ((lane >> 2) & 3);
    const int scol = skp * 8;
    const ushort_t* ga  = A + (size_t)(bm + srow) * K + scol;
    const ushort_t* gb0 = B + (size_t)(bn + srow) * K + scol;
    const ushort_t* gb1 = B + (size_t)(bn + 64 + srow) * K + scol;
    const int fcol = ((quad ^ (l15 & 3)) * 8);

    floatx4 acc[2][4];
    #pragma unroll
    for (int mt = 0; mt < 2; ++mt)
        #pragma unroll
        for (int nt = 0; nt < 4; ++nt) acc[mt][nt] = (floatx4){0.f, 0.f, 0.f, 0.f};

    for (int k0 = 0; k0 < K; k0 += 32) {
        gload16(ga  + k0, &Ah[w * 16][0]);
        gload16(gb0 + k0, &Bh[w * 16][0]);
        gload16(gb1 + k0, &Bh[64 + w * 16][0]);
        __syncthreads();
        short8 ah[2], bh[4];
        #pragma unroll
        for (int x = 0; x < 2; ++x)
            ah[x] = *(const short8*)&Ah[wm * 32 + x * 16 + l15][fcol];
        #pragma unroll
        for (int x = 0; x < 4; ++x)
            bh[x] = *(const short8*)&Bh[wn * 64 + x * 16 + l15][fcol];
        #pragma unroll
        for (int mt = 0; mt < 2; ++mt)
            #pragma unroll
            for (int nt = 0; nt < 4; ++nt)
                acc[mt][nt] = __builtin_amdgcn_mfma_f32_16x16x32_bf16(ah[mt], bh[nt], acc[mt][nt], 0, 0, 0);
        __syncthreads();
    }
    #pragma unroll
    for (int mt = 0; mt < 2; ++mt)
        #pragma unroll
        for (int r = 0; r < 4; ++r) {
            size_t row = (size_t)(bm + wm * 32 + mt * 16 + quad * 4 + r) * N;
            #pragma unroll
            for (int nt = 0; nt < 4; ++nt) {
                int col = bn + wn * 64 + nt * 16 + l15;
                C[row + col] = acc[mt][nt][r] + bias[col];
            }
        }
}

// ---------------- MFMA flash attention v7 ----------------
// v6 -> v7: eliminate the Ps LDS round-trip. QK^T's sc layout
// [q=l15][key=quad*4+r] IS the 16x16x16 A/B fragment layout, so packed P
// feeds PV directly: out[tt][dt] += mfma16(vA[c][dt], pB[c]).
// vA[c][dt] = V[key=c*16+quad*4+j][d=dt*16+l15] as b64 reads from swizzled Vt.
// madd moves from LDS to global (16KB, L1/L2-hot).
// LDS traffic: 28KB -> 16KB per wave per kt (was at the 85 B/cy/CU LDS roof).
__global__ __launch_bounds__(256, 2) void flash_v7(
    const ushort_t* __restrict__ qkv, const ushort_t* __restrict__ vtg,
    const float* __restrict__ maddg, ushort_t* __restrict__ attn)
{
    __shared__ ushort_t Ks[2][64][64];       // [buf][key][dchunk ^ (key&7)]
    __shared__ ushort_t Vt[2][64][64];       // [buf][d][keychunk ^ (d&7)]

    const int blk = blockIdx.x;              // 0..511
    const int xcd = blk & 7, rr = blk >> 3;
    const int qi = rr & 15, g = xcd + 8 * (rr >> 4);     // g in [0,32)
    const int b = g >> 4, h = g & 15, q0 = qi * 128;

    const int t = threadIdx.x, wave = t >> 6, lane = t & 63;
    const int l15 = lane & 15, quad = lane >> 4;
    const size_t bS = (size_t)b * 2048;
    const float c1 = 0.125f * 1.44269504088896340736f;   // (1/sqrt(D))*log2(e)

    short8 qf[2][2];
    #pragma unroll
    for (int tt = 0; tt < 2; ++tt) {
        int q = q0 + wave * 32 + tt * 16 + l15;
        const ushort_t* qp = qkv + (bS + q) * 2048 + h * 64;
        qf[tt][0] = *(const short8*)(qp + quad * 8);
        qf[tt][1] = *(const short8*)(qp + 32 + quad * 8);
    }

    const int srow  = wave * 16 + (lane >> 3);                 // row (key or d)
    const int schnk = ((lane & 7) ^ ((lane >> 3) & 7)) * 8;    // swizzled chunk
    const ushort_t* gK = qkv + (bS + srow) * 2048 + 1024 + h * 64 + schnk;
    const ushort_t* gV = vtg + ((size_t)(b * 16 + h) * 64 + srow) * 2048 + schnk;
    const float* gM = maddg + b * 2048;

    gload16(gK,            &Ks[0][wave * 16][0]);
    gload16(gK + 8 * 2048, &Ks[0][wave * 16 + 8][0]);
    gload16(gV,            &Vt[0][wave * 16][0]);
    gload16(gV + 8 * 2048, &Vt[0][wave * 16 + 8][0]);
    __syncthreads();

    floatx4 outacc[2][4];
    float lsum[2] = {0.f, 0.f};
    #pragma unroll
    for (int tt = 0; tt < 2; ++tt)
        #pragma unroll
        for (int dt = 0; dt < 4; ++dt) outacc[tt][dt] = (floatx4){0.f, 0.f, 0.f, 0.f};

    int cur = 0;
    for (int kt = 0; kt < 32; ++kt) {
        const int k0 = kt * 64;
        {
            const int kn = (kt + 1 < 32) ? (kt + 1) * 64 : 0;   // wrap: harmless
            const int nb = cur ^ 1;
            gload16(gK + (size_t)kn * 2048,            &Ks[nb][wave * 16][0]);
            gload16(gK + (size_t)(kn + 8) * 2048,      &Ks[nb][wave * 16 + 8][0]);
            gload16(gV + kn,                           &Vt[nb][wave * 16][0]);
            gload16(gV + kn + 8 * 2048,                &Vt[nb][wave * 16 + 8][0]);
        }
        // mask-add terms from global (L1-hot, 8KB/batch); issue early
        float4 madd4[4];
        #pragma unroll
        for (int c = 0; c < 4; ++c)
            madd4[c] = *(const float4*)&gM[k0 + c * 16 + quad * 4];

        short8 kf[2][4];
        #pragma unroll
        for (int kc = 0; kc < 2; ++kc)
            #pragma unroll
            for (int c = 0; c < 4; ++c) {
                int ch = ((kc * 4 + quad) ^ (l15 & 7)) * 8;
                kf[kc][c] = *(const short8*)&Ks[cur][c * 16 + l15][ch];
            }
        // V fragments for x16 PV: vA[c][dt][j] = V[key=c*16+quad*4+j][d=dt*16+l15]
        short4b vA[4][4];
        #pragma unroll
        for (int c = 0; c < 4; ++c) {
            const int vby = (((2 * c + (quad >> 1)) ^ (l15 & 7)) * 16 + (quad & 1) * 8);
            #pragma unroll
            for (int dt = 0; dt < 4; ++dt)
                vA[c][dt] = *(const short4b*)((const char*)&Vt[cur][dt * 16 + l15][0] + vby);
        }

        #pragma unroll
        for (int tt = 0; tt < 2; ++tt) {
            floatx4 sc[4];
            #pragma unroll
            for (int c = 0; c < 4; ++c) {
                sc[c] = (floatx4){0.f, 0.f, 0.f, 0.f};
                sc[c] = __builtin_amdgcn_mfma_f32_16x16x32_bf16(kf[0][c], qf[tt][0], sc[c], 0, 0, 0);
                sc[c] = __builtin_amdgcn_mfma_f32_16x16x32_bf16(kf[1][c], qf[tt][1], sc[c], 0, 0, 0);
            }
            #pragma unroll
            for (int c = 0; c < 4; ++c) {
                float p0 = hexp2(fmaf(sc[c][0], c1, madd4[c].x));
                float p1 = hexp2(fmaf(sc[c][1], c1, madd4[c].y));
                float p2 = hexp2(fmaf(sc[c][2], c1, madd4[c].z));
                float p3 = hexp2(fmaf(sc[c][3], c1, madd4[c].w));
                lsum[tt] += (p0 + p1) + (p2 + p3);
                uint2 u;
                u.x = pack2bf(p0, p1);
                u.y = pack2bf(p2, p3);
                short4b pb = __builtin_bit_cast(short4b, u);
                #pragma unroll
                for (int dt = 0; dt < 4; ++dt)
                    outacc[tt][dt] = mfma16(vA[c][dt], pb, outacc[tt][dt]);
            }
        }
        __syncthreads();
        cur ^= 1;
    }

    #pragma unroll
    for (int tt = 0; tt < 2; ++tt) {
        lsum[tt] += __shfl_xor(lsum[tt], 16);
        lsum[tt] += __shfl_xor(lsum[tt], 32);
        float inv = 1.f / lsum[tt];
        int q = q0 + wave * 32 + tt * 16 + l15;
        ushort_t* orow = attn + (bS + q) * 1024 + h * 64;
        #pragma unroll
        for (int dt = 0; dt < 4; ++dt) {
            uint2 pk;
            pk.x = pack2bf(outacc[tt][dt][0] * inv, outacc[tt][dt][1] * inv);
            pk.y = pack2bf(outacc[tt][dt][2] * inv, outacc[tt][dt][3] * inv);
            *(uint2*)&orow[dt * 16 + quad * 4] = pk;
        }
    }
}

extern "C" void kernel_launch(void* const* d_in, const int* in_sizes, int n_in,
                              void* d_out, int out_size, void* d_ws, size_t ws_size,
                              hipStream_t stream) {
    const float* x    = (const float*)d_in[0];   // (2,2048,1024)
    const int*   mask = (const int*)  d_in[1];   // (2,2048)
    const float* Wqkv = (const float*)d_in[2];   // (1024,3072)
    const float* bqkv = (const float*)d_in[3];   // (3072,)
    const float* Wout = (const float*)d_in[4];   // (1024,1024)
    const float* bout = (const float*)d_in[5];   // (1024,)
    float* out = (float*)d_out;                  // (2,2048,1024) fp32

    char* ws = (char*)d_ws;
    ushort_t* xb    = (ushort_t*)(ws);                   //  8 MB [0, 8388608)
    ushort_t* wqT   = (ushort_t*)(ws + 8388608);         //  6 MB [.., 14680064)
    ushort_t* qkvb  = (ushort_t*)(ws + 14680064);        // 16 MB [.., 31457280) Q,K only
    ushort_t* vtg   = (ushort_t*)(ws + 31457280);        //  8 MB [.., 39845888)
    ushort_t* attnb = (ushort_t*)(ws + 39845888);        //  8 MB [.., 48234496)
    ushort_t* woT   = (ushort_t*)(ws + 48234496);        //  2 MB [.., 50331648)
    float*    maddg = (float*)   (ws + 50331648);        // 16 KB

    const int M = 4096, E = 1024, N3 = 3072;

    prep<<<dim3(8208), dim3(256), 0, stream>>>(
        x, xb, Wqkv, wqT, Wout, woT, mask, maddg);

    gemm_qkv<<<dim3(N3 / 128, M / 128), dim3(256), 0, stream>>>(
        xb, wqT, bqkv, qkvb, vtg);

    flash_v7<<<dim3(512), dim3(256), 0, stream>>>(qkvb, vtg, maddg, attnb);

    gemm_bf16_f32_64<<<dim3(E / 128, M / 64), dim3(256), 0, stream>>>(
        attnb, woT, bout, out, M, E, E);
}

// Round 2
// 196.750 us; speedup vs baseline: 1.0691x; 1.0691x over previous
//
#include <hip/hip_runtime.h>

// B=2, S=2048, E=1024, H=16, D=64; rows = B*S = 4096; 3E = 3072.

typedef __attribute__((ext_vector_type(8))) short short8;     // 8 bf16 (A/B frag, x32)
typedef __attribute__((ext_vector_type(4))) short short4b;    // 4 bf16 (A/B frag, x16)
typedef __attribute__((ext_vector_type(4))) float floatx4;    // C/D frag
typedef unsigned short ushort_t;

static __device__ __forceinline__ ushort_t f2bf(float f) {
    unsigned u = __float_as_uint(f);
    u += 0x7fffu + ((u >> 16) & 1u);      // round-to-nearest-even
    return (ushort_t)(u >> 16);
}
static __device__ __forceinline__ float bf2f(ushort_t h) {
    return __uint_as_float(((unsigned)h) << 16);
}
#if __has_builtin(__builtin_amdgcn_cvt_pk_bf16_f32)
typedef __attribute__((ext_vector_type(2))) __bf16 bf16x2_t;
static __device__ __forceinline__ unsigned pack2bf(float a, float b) {
    bf16x2_t r = __builtin_amdgcn_cvt_pk_bf16_f32(a, b);
    return __builtin_bit_cast(unsigned, r);
}
#else
static __device__ __forceinline__ unsigned pack2bf(float a, float b) {
    return (unsigned)f2bf(a) | ((unsigned)f2bf(b) << 16);
}
#endif
static __device__ __forceinline__ float hexp2(float x) {
    return __builtin_amdgcn_exp2f(x);
}
// async global->LDS, 16B per lane; LDS dest = wave-uniform base + lane*16
static __device__ __forceinline__ void gload16(const void* g, void* l) {
    __builtin_amdgcn_global_load_lds(
        (const __attribute__((address_space(1))) unsigned int*)g,
        (__attribute__((address_space(3))) unsigned int*)l, 16, 0, 0);
}

// 16x16x16 bf16 MFMA: A/B = 4 bf16 (2 VGPRs).
static __device__ __forceinline__ floatx4 mfma16(short4b a, short4b b, floatx4 c) {
#if __has_builtin(__builtin_amdgcn_mfma_f32_16x16x16_bf16)
    return __builtin_amdgcn_mfma_f32_16x16x16_bf16(a, b, c, 0, 0, 0);
#elif __has_builtin(__builtin_amdgcn_mfma_f32_16x16x16bf16_1k)
    return __builtin_amdgcn_mfma_f32_16x16x16bf16_1k(a, b, c, 0, 0, 0);
#else
    asm("v_mfma_f32_16x16x16_bf16 %0, %1, %2, %0" : "+v"(c) : "v"(a), "v"(b));
    return c;
#endif
}

// ---------------- fused prep kernel ----------------
__global__ __launch_bounds__(256) void prep(
    const float* __restrict__ x, ushort_t* __restrict__ xb,
    const float* __restrict__ Wqkv, ushort_t* __restrict__ wqT,
    const float* __restrict__ Wout, ushort_t* __restrict__ woT,
    const int* __restrict__ mask, float* __restrict__ maddg)
{
    __shared__ float tile[32][33];
    const int bk = blockIdx.x;
    const int t = threadIdx.x;
    if (bk < 4096) {
        int i = bk * 256 + t;
        float4 v = ((const float4*)x)[i];
        uint2 o;
        o.x = pack2bf(v.x, v.y);
        o.y = pack2bf(v.z, v.w);
        ((uint2*)xb)[i] = o;
        return;
    }
    if (bk < 8192) {
        const float* W; ushort_t* WT; int K, N, id;
        if (bk < 7168) { W = Wqkv; WT = wqT; K = 1024; N = 3072; id = bk - 4096;
                         int nb = (id % 96) * 32, kb = (id / 96) * 32;
                         const int r = t >> 3, c4 = (t & 7) * 4;
                         float4 v = *(const float4*)&W[(size_t)(kb + r) * N + nb + c4];
                         tile[r][c4+0]=v.x; tile[r][c4+1]=v.y; tile[r][c4+2]=v.z; tile[r][c4+3]=v.w;
                         __syncthreads();
                         uint2 o;
                         o.x = pack2bf(tile[c4+0][r], tile[c4+1][r]);
                         o.y = pack2bf(tile[c4+2][r], tile[c4+3][r]);
                         ((uint2*)WT)[((size_t)(nb + r) * K + kb + c4) >> 2] = o;
        } else {         W = Wout; WT = woT; K = 1024; N = 1024; id = bk - 7168;
                         int nb = (id % 32) * 32, kb = (id / 32) * 32;
                         const int r = t >> 3, c4 = (t & 7) * 4;
                         float4 v = *(const float4*)&W[(size_t)(kb + r) * N + nb + c4];
                         tile[r][c4+0]=v.x; tile[r][c4+1]=v.y; tile[r][c4+2]=v.z; tile[r][c4+3]=v.w;
                         __syncthreads();
                         uint2 o;
                         o.x = pack2bf(tile[c4+0][r], tile[c4+1][r]);
                         o.y = pack2bf(tile[c4+2][r], tile[c4+3][r]);
                         ((uint2*)WT)[((size_t)(nb + r) * K + kb + c4) >> 2] = o;
        }
        return;
    }
    {
        int i = (bk - 8192) * 256 + t;      // 4096 total
        maddg[i] = (mask[i] ? 0.f : -1e30f) - 24.0f;
    }
}

// ---------------- GEMM1: qkv projection ----------------
__global__ __launch_bounds__(256, 3) void gemm_qkv(
    const ushort_t* __restrict__ A, const ushort_t* __restrict__ B,
    const float* __restrict__ bias, ushort_t* __restrict__ qkvb,
    ushort_t* __restrict__ vtg)
{
    const int K = 1024;
    __shared__ ushort_t Ah[128][32], Bh[128][32];
    __shared__ ushort_t Tb[64][136];         // V-transpose bounce, 16B-aligned rows
    const int bn = blockIdx.x * 128, bm = blockIdx.y * 128;
    const int t = threadIdx.x, w = t >> 6, lane = t & 63;
    const int l15 = lane & 15, quad = lane >> 4;
    const int wm = w >> 1, wn = w & 1;

    const int srow = w * 32 + (lane >> 2);
    const int skp  = (lane & 3) ^ ((lane >> 2) & 3);     // swizzled global k-part
    const int scol = skp * 8;
    const ushort_t* ga = A + (size_t)(bm + srow) * K + scol;
    const ushort_t* gb = B + (size_t)(bn + srow) * K + scol;
    const size_t rstep = (size_t)16 * K;
    const int fcol = ((quad ^ (l15 & 3)) * 8);           // frag read col (deswizzle)

    floatx4 acc[4][4];
    #pragma unroll
    for (int mt = 0; mt < 4; ++mt)
        #pragma unroll
        for (int nt = 0; nt < 4; ++nt) acc[mt][nt] = (floatx4){0.f, 0.f, 0.f, 0.f};

    for (int k0 = 0; k0 < K; k0 += 32) {
        #pragma unroll
        for (int i = 0; i < 2; ++i) {
            gload16(ga + i * rstep + k0, &Ah[w * 32 + i * 16][0]);
            gload16(gb + i * rstep + k0, &Bh[w * 32 + i * 16][0]);
        }
        __syncthreads();
        short8 ah[4], bh[4];
        #pragma unroll
        for (int x = 0; x < 4; ++x) {
            ah[x] = *(const short8*)&Ah[wm * 64 + x * 16 + l15][fcol];
            bh[x] = *(const short8*)&Bh[wn * 64 + x * 16 + l15][fcol];
        }
        #pragma unroll
        for (int mt = 0; mt < 4; ++mt)
            #pragma unroll
            for (int nt = 0; nt < 4; ++nt)
                acc[mt][nt] = __builtin_amdgcn_mfma_f32_16x16x32_bf16(ah[mt], bh[nt], acc[mt][nt], 0, 0, 0);
        __syncthreads();
    }

    if (bn < 2048) {
        #pragma unroll
        for (int mt = 0; mt < 4; ++mt)
            #pragma unroll
            for (int r = 0; r < 4; ++r) {
                size_t row = (size_t)(bm + wm * 64 + mt * 16 + quad * 4 + r) * 2048;
                #pragma unroll
                for (int nt = 0; nt < 4; ++nt) {
                    int col = bn + wn * 64 + nt * 16 + l15;
                    qkvb[row + col] = f2bf(acc[mt][nt][r] + bias[col]);
                }
            }
    } else {
        // V block: LDS bounce -> vtg[b][h][d][s], one head (64 d) per pass
        const int h0 = (bn - 2048) >> 6;
        const int b  = bm >> 11, s0 = bm & 2047;
        #pragma unroll
        for (int hh = 0; hh < 2; ++hh) {
            if (wn == hh) {
                #pragma unroll
                for (int mt = 0; mt < 4; ++mt)
                    #pragma unroll
                    for (int nt = 0; nt < 4; ++nt) {
                        int d = nt * 16 + l15;
                        int sb = wm * 64 + mt * 16 + quad * 4;
                        float bv = bias[bn + hh * 64 + nt * 16 + l15];
                        uint2 pk;
                        pk.x = pack2bf(acc[mt][nt][0] + bv, acc[mt][nt][1] + bv);
                        pk.y = pack2bf(acc[mt][nt][2] + bv, acc[mt][nt][3] + bv);
                        *(uint2*)&Tb[d][sb] = pk;
                    }
            }
            __syncthreads();
            ushort_t* vbase = vtg + ((size_t)((b * 16 + h0 + hh) * 64)) * 2048 + s0;
            #pragma unroll
            for (int it = 0; it < 4; ++it) {
                int idx = t + it * 256;          // 0..1023
                int d = idx >> 4, ch = idx & 15;
                uint4 v = *(const uint4*)&Tb[d][ch * 8];
                *(uint4*)&vbase[(size_t)d * 2048 + ch * 8] = v;
            }
            __syncthreads();
        }
    }
}

// ---------------- GEMM3: 64x128 tile, fp32 output ----------------
__global__ __launch_bounds__(256, 3) void gemm_bf16_f32_64(
    const ushort_t* __restrict__ A, const ushort_t* __restrict__ B,
    const float* __restrict__ bias, float* __restrict__ C,
    int M, int N, int K)
{
    __shared__ ushort_t Ah[64][32], Bh[128][32];
    const int bn = blockIdx.x * 128, bm = blockIdx.y * 64;
    const int t = threadIdx.x, w = t >> 6, lane = t & 63;
    const int l15 = lane & 15, quad = lane >> 4;
    const int wm = w >> 1, wn = w & 1;          // wave-tile 32x64

    const int srow = w * 16 + (lane >> 2);
    const int skp  = (lane & 3) ^ ((lane >> 2) & 3);
    const int scol = skp * 8;
    const ushort_t* ga  = A + (size_t)(bm + srow) * K + scol;
    const ushort_t* gb0 = B + (size_t)(bn + srow) * K + scol;
    const ushort_t* gb1 = B + (size_t)(bn + 64 + srow) * K + scol;
    const int fcol = ((quad ^ (l15 & 3)) * 8);

    floatx4 acc[2][4];
    #pragma unroll
    for (int mt = 0; mt < 2; ++mt)
        #pragma unroll
        for (int nt = 0; nt < 4; ++nt) acc[mt][nt] = (floatx4){0.f, 0.f, 0.f, 0.f};

    for (int k0 = 0; k0 < K; k0 += 32) {
        gload16(ga  + k0, &Ah[w * 16][0]);
        gload16(gb0 + k0, &Bh[w * 16][0]);
        gload16(gb1 + k0, &Bh[64 + w * 16][0]);
        __syncthreads();
        short8 ah[2], bh[4];
        #pragma unroll
        for (int x = 0; x < 2; ++x)
            ah[x] = *(const short8*)&Ah[wm * 32 + x * 16 + l15][fcol];
        #pragma unroll
        for (int x = 0; x < 4; ++x)
            bh[x] = *(const short8*)&Bh[wn * 64 + x * 16 + l15][fcol];
        #pragma unroll
        for (int mt = 0; mt < 2; ++mt)
            #pragma unroll
            for (int nt = 0; nt < 4; ++nt)
                acc[mt][nt] = __builtin_amdgcn_mfma_f32_16x16x32_bf16(ah[mt], bh[nt], acc[mt][nt], 0, 0, 0);
        __syncthreads();
    }
    #pragma unroll
    for (int mt = 0; mt < 2; ++mt)
        #pragma unroll
        for (int r = 0; r < 4; ++r) {
            size_t row = (size_t)(bm + wm * 32 + mt * 16 + quad * 4 + r) * N;
            #pragma unroll
            for (int nt = 0; nt < 4; ++nt) {
                int col = bn + wn * 64 + nt * 16 + l15;
                C[row + col] = acc[mt][nt][r] + bias[col];
            }
        }
}

// ---------------- MFMA flash attention v8 ----------------
// v7 -> v8: occupancy. 8 waves/block, 16 q-rows/wave (tt loop removed),
// grid stays 512 -> 16 waves/CU = 4 waves/SIMD (was 2). Per-kt VALU
// (softmax), MFMA, and LDS phases of different waves now overlap.
// Staging: 1 gload16/buffer/wave (rows wave*8..wave*8+8).
// s_setprio(1) around MFMA clusters (T5; 8 waves give role diversity).
__global__ __launch_bounds__(512, 4) void flash_v8(
    const ushort_t* __restrict__ qkv, const ushort_t* __restrict__ vtg,
    const float* __restrict__ maddg, ushort_t* __restrict__ attn)
{
    __shared__ ushort_t Ks[2][64][64];       // [buf][key][dchunk ^ (key&7)]
    __shared__ ushort_t Vt[2][64][64];       // [buf][d][keychunk ^ (d&7)]

    const int blk = blockIdx.x;              // 0..511
    const int xcd = blk & 7, rr = blk >> 3;
    const int qi = rr & 15, g = xcd + 8 * (rr >> 4);     // g in [0,32)
    const int b = g >> 4, h = g & 15, q0 = qi * 128;

    const int t = threadIdx.x, wave = t >> 6, lane = t & 63;
    const int l15 = lane & 15, quad = lane >> 4;
    const size_t bS = (size_t)b * 2048;
    const float c1 = 0.125f * 1.44269504088896340736f;   // (1/sqrt(D))*log2(e)

    short8 qf[2];
    {
        int q = q0 + wave * 16 + l15;
        const ushort_t* qp = qkv + (bS + q) * 2048 + h * 64;
        qf[0] = *(const short8*)(qp + quad * 8);
        qf[1] = *(const short8*)(qp + 32 + quad * 8);
    }

    const int srow  = wave * 8 + (lane >> 3);                  // row (key or d)
    const int schnk = ((lane & 7) ^ ((lane >> 3) & 7)) * 8;    // swizzled chunk
    const ushort_t* gK = qkv + (bS + srow) * 2048 + 1024 + h * 64 + schnk;
    const ushort_t* gV = vtg + ((size_t)(b * 16 + h) * 64 + srow) * 2048 + schnk;
    const float* gM = maddg + b * 2048;

    gload16(gK, &Ks[0][wave * 8][0]);
    gload16(gV, &Vt[0][wave * 8][0]);
    __syncthreads();

    floatx4 outacc[4];
    float lsum = 0.f;
    #pragma unroll
    for (int dt = 0; dt < 4; ++dt) outacc[dt] = (floatx4){0.f, 0.f, 0.f, 0.f};

    int cur = 0;
    for (int kt = 0; kt < 32; ++kt) {
        const int k0 = kt * 64;
        {
            const int kn = (kt + 1 < 32) ? (kt + 1) * 64 : 0;   // wrap: harmless
            const int nb = cur ^ 1;
            gload16(gK + (size_t)kn * 2048, &Ks[nb][wave * 8][0]);
            gload16(gV + kn,                &Vt[nb][wave * 8][0]);
        }
        // mask-add terms from global (L1-hot); issue early
        float4 madd4[4];
        #pragma unroll
        for (int c = 0; c < 4; ++c)
            madd4[c] = *(const float4*)&gM[k0 + c * 16 + quad * 4];

        short8 kf[2][4];
        #pragma unroll
        for (int kc = 0; kc < 2; ++kc)
            #pragma unroll
            for (int c = 0; c < 4; ++c) {
                int ch = ((kc * 4 + quad) ^ (l15 & 7)) * 8;
                kf[kc][c] = *(const short8*)&Ks[cur][c * 16 + l15][ch];
            }
        // V fragments for x16 PV: vA[c][dt][j] = V[key=c*16+quad*4+j][d=dt*16+l15]
        short4b vA[4][4];
        #pragma unroll
        for (int c = 0; c < 4; ++c) {
            const int vby = (((2 * c + (quad >> 1)) ^ (l15 & 7)) * 16 + (quad & 1) * 8);
            #pragma unroll
            for (int dt = 0; dt < 4; ++dt)
                vA[c][dt] = *(const short4b*)((const char*)&Vt[cur][dt * 16 + l15][0] + vby);
        }

        floatx4 sc[4];
        __builtin_amdgcn_s_setprio(1);
        #pragma unroll
        for (int c = 0; c < 4; ++c) {
            sc[c] = (floatx4){0.f, 0.f, 0.f, 0.f};
            sc[c] = __builtin_amdgcn_mfma_f32_16x16x32_bf16(kf[0][c], qf[0], sc[c], 0, 0, 0);
            sc[c] = __builtin_amdgcn_mfma_f32_16x16x32_bf16(kf[1][c], qf[1], sc[c], 0, 0, 0);
        }
        __builtin_amdgcn_s_setprio(0);
        #pragma unroll
        for (int c = 0; c < 4; ++c) {
            float p0 = hexp2(fmaf(sc[c][0], c1, madd4[c].x));
            float p1 = hexp2(fmaf(sc[c][1], c1, madd4[c].y));
            float p2 = hexp2(fmaf(sc[c][2], c1, madd4[c].z));
            float p3 = hexp2(fmaf(sc[c][3], c1, madd4[c].w));
            lsum += (p0 + p1) + (p2 + p3);
            uint2 u;
            u.x = pack2bf(p0, p1);
            u.y = pack2bf(p2, p3);
            short4b pb = __builtin_bit_cast(short4b, u);
            __builtin_amdgcn_s_setprio(1);
            #pragma unroll
            for (int dt = 0; dt < 4; ++dt)
                outacc[dt] = mfma16(vA[c][dt], pb, outacc[dt]);
            __builtin_amdgcn_s_setprio(0);
        }
        __syncthreads();
        cur ^= 1;
    }

    {
        lsum += __shfl_xor(lsum, 16);
        lsum += __shfl_xor(lsum, 32);
        float inv = 1.f / lsum;
        int q = q0 + wave * 16 + l15;
        ushort_t* orow = attn + (bS + q) * 1024 + h * 64;
        #pragma unroll
        for (int dt = 0; dt < 4; ++dt) {
            uint2 pk;
            pk.x = pack2bf(outacc[dt][0] * inv, outacc[dt][1] * inv);
            pk.y = pack2bf(outacc[dt][2] * inv, outacc[dt][3] * inv);
            *(uint2*)&orow[dt * 16 + quad * 4] = pk;
        }
    }
}

extern "C" void kernel_launch(void* const* d_in, const int* in_sizes, int n_in,
                              void* d_out, int out_size, void* d_ws, size_t ws_size,
                              hipStream_t stream) {
    const float* x    = (const float*)d_in[0];   // (2,2048,1024)
    const int*   mask = (const int*)  d_in[1];   // (2,2048)
    const float* Wqkv = (const float*)d_in[2];   // (1024,3072)
    const float* bqkv = (const float*)d_in[3];   // (3072,)
    const float* Wout = (const float*)d_in[4];   // (1024,1024)
    const float* bout = (const float*)d_in[5];   // (1024,)
    float* out = (float*)d_out;                  // (2,2048,1024) fp32

    char* ws = (char*)d_ws;
    ushort_t* xb    = (ushort_t*)(ws);                   //  8 MB [0, 8388608)
    ushort_t* wqT   = (ushort_t*)(ws + 8388608);         //  6 MB [.., 14680064)
    ushort_t* qkvb  = (ushort_t*)(ws + 14680064);        // 16 MB [.., 31457280) Q,K only
    ushort_t* vtg   = (ushort_t*)(ws + 31457280);        //  8 MB [.., 39845888)
    ushort_t* attnb = (ushort_t*)(ws + 39845888);        //  8 MB [.., 48234496)
    ushort_t* woT   = (ushort_t*)(ws + 48234496);        //  2 MB [.., 50331648)
    float*    maddg = (float*)   (ws + 50331648);        // 16 KB

    const int M = 4096, E = 1024, N3 = 3072;

    prep<<<dim3(8208), dim3(256), 0, stream>>>(
        x, xb, Wqkv, wqT, Wout, woT, mask, maddg);

    gemm_qkv<<<dim3(N3 / 128, M / 128), dim3(256), 0, stream>>>(
        xb, wqT, bqkv, qkvb, vtg);

    flash_v8<<<dim3(512), dim3(512), 0, stream>>>(qkvb, vtg, maddg, attnb);

    gemm_bf16_f32_64<<<dim3(E / 128, M / 64), dim3(256), 0, stream>>>(
        attnb, woT, bout, out, M, E, E);
}